// Round 1
// baseline (1343.110 us; speedup 1.0000x reference)
//
#include <hip/hip_runtime.h>
#include <math.h>

// EndPointAggregator: out[s] = concat(emb[start_s], emb[end_s], tanh(dist_s * w + b))
// SEQ_LEN=4096, DIM=768, N_SPANS=200000, OUT_COLS=1538.
// Write-bandwidth-bound: 1.23 GB out, ~14 MB unique reads (L2/L3 resident).

typedef float floatx2 __attribute__((ext_vector_type(2)));

#define DIM 768
#define F2_PER_ROW 384      // 768 floats / 2
#define OUT_F2 769          // 1538 floats / 2 (last float2 = the tanh pair)
#define BLOCK 128

__global__ __launch_bounds__(BLOCK)
void endpoint_agg_kernel(const floatx2* __restrict__ emb,   // [4096][384] float2, rows 3072B-aligned
                         const int* __restrict__ spans,     // [N][2] int32
                         const float* __restrict__ dw,      // dist_w: 2 floats
                         const float* __restrict__ db,      // dist_b: 2 floats
                         float* __restrict__ out,           // [N][1538]
                         int n)
{
    const int s = blockIdx.x;
    if (s >= n) return;

    const int start = spans[2 * s];
    const int end   = spans[2 * s + 1];

    const floatx2* __restrict__ srow = emb + (size_t)start * F2_PER_ROW;
    const floatx2* __restrict__ erow = emb + (size_t)end   * F2_PER_ROW;
    // Row base byte offset = s*6152: 8B-aligned always (not 16B) -> float2 stores.
    floatx2* __restrict__ orow = (floatx2*)(out + (size_t)s * (size_t)(2 * OUT_F2));

    const int tid = threadIdx.x;

    #pragma unroll
    for (int it = 0; it < 6; ++it) {
        const int i = tid + it * BLOCK;            // 0..767, fully utilized
        floatx2 v = (i < F2_PER_ROW) ? srow[i] : erow[i - F2_PER_ROW];
        __builtin_nontemporal_store(v, orow + i);  // streaming: don't pollute L2/L3
    }

    if (tid == 0) {
        const float dist = (float)(end - start);
        floatx2 d;
        d.x = tanhf(dist * dw[0] + db[0]);
        d.y = tanhf(dist * dw[1] + db[1]);
        __builtin_nontemporal_store(d, orow + 768);
    }
}

extern "C" void kernel_launch(void* const* d_in, const int* in_sizes, int n_in,
                              void* d_out, int out_size, void* d_ws, size_t ws_size,
                              hipStream_t stream) {
    const floatx2* emb = (const floatx2*)d_in[0];      // sentence_embeddings [4096,768] f32
    const int* spans   = (const int*)d_in[1];          // sentence_spans [N,2] int
    const float* dw    = (const float*)d_in[2];        // dist_w [2,1]
    const float* db    = (const float*)d_in[3];        // dist_b [2]
    float* out         = (float*)d_out;

    const int n = in_sizes[1] / 2;                     // N_SPANS
    dim3 grid(n), block(BLOCK);
    hipLaunchKernelGGL(endpoint_agg_kernel, grid, block, 0, stream,
                       emb, spans, dw, db, out, n);
}